// Round 11
// baseline (242.249 us; speedup 1.0000x reference)
//
#include <hip/hip_runtime.h>

// Problem constants (z: [16, 64, 64, 64] f32, codebook: [2048, 64] f32)
#define C_DIM   64
#define HW      4096        // H*W
#define NROWS   65536       // B*H*W
#define N_E     2048
#define N_ELEM  4194304     // B*C*H*W
// Output layout (flat): z_q_out 4194304 | loss 1 | perplexity 1 | indices 65536
#define OUT_LOSS_OFF 4194304
#define OUT_PPL_OFF  4194305
#define OUT_IDX_OFF  4194306

#define ROWS_B   128                 // rows per block -> 512 blocks = 2/CU
#define NBLOCKS  (NROWS / ROWS_B)    // 512
#define NTILE    (N_E / 16)          // 128 code tiles of 16 codes

typedef __attribute__((ext_vector_type(8))) short bf16x8;
typedef __attribute__((ext_vector_type(4))) float f32x4;

// round-to-nearest-even f32 -> bf16 bits
__device__ __forceinline__ unsigned short f2bf(float f) {
    unsigned u = __float_as_uint(f);
    return (unsigned short)((u + 0x7FFFu + ((u >> 16) & 1u)) >> 16);
}
__device__ __forceinline__ float bf2f(unsigned short b) {
    return __uint_as_float(((unsigned)b) << 16);
}

// Split 8 consecutive f32 (two float4) into 3 bf16 terms. Static indices only.
// Bit-identical math/order to the old prep kernel -> absmax 0.0 preserved.
__device__ __forceinline__ void split8(const float4 a, const float4 b,
                                       bf16x8* s1v, bf16x8* s2v, bf16x8* s3v)
{
    const float v[8] = {a.x, a.y, a.z, a.w, b.x, b.y, b.z, b.w};
    bf16x8 t1, t2, t3;
#pragma unroll
    for (int i = 0; i < 8; ++i) {
        const unsigned short s1 = f2bf(v[i]);
        const float r1 = v[i] - bf2f(s1);
        const unsigned short s2 = f2bf(r1);
        const float r2 = r1 - bf2f(s2);
        t1[i] = (short)s1;
        t2[i] = (short)s2;
        t3[i] = (short)f2bf(r2);
    }
    *s1v = t1; *s2v = t2; *s3v = t3;
}

#define M16(A_, B_, C_) __builtin_amdgcn_mfma_f32_16x16x32_bf16((A_), (B_), (C_), 0, 0, 0)

// 8 split-passes (sc,sz): (1,1)(1,2)(2,1)(2,2)(1,3)(3,1)(2,3)(3,2); only (3,3) dropped.
// AA[s*2+k2]; NT = n-tile literal (0..1).
#define PASS8(AA, ACC, NT)                                                      \
    ACC = M16(AA[0], zf[0][NT][0], ACC); ACC = M16(AA[1], zf[0][NT][1], ACC);   \
    ACC = M16(AA[0], zf[1][NT][0], ACC); ACC = M16(AA[1], zf[1][NT][1], ACC);   \
    ACC = M16(AA[2], zf[0][NT][0], ACC); ACC = M16(AA[3], zf[0][NT][1], ACC);   \
    ACC = M16(AA[2], zf[1][NT][0], ACC); ACC = M16(AA[3], zf[1][NT][1], ACC);   \
    ACC = M16(AA[0], zf[2][NT][0], ACC); ACC = M16(AA[1], zf[2][NT][1], ACC);   \
    ACC = M16(AA[4], zf[0][NT][0], ACC); ACC = M16(AA[5], zf[0][NT][1], ACC);   \
    ACC = M16(AA[2], zf[2][NT][0], ACC); ACC = M16(AA[3], zf[2][NT][1], ACC);   \
    ACC = M16(AA[4], zf[1][NT][0], ACC); ACC = M16(AA[5], zf[1][NT][1], ACC);

// Load raw codebook rows for tile T_: lane reads cb[c = T_*16 + l15]
// cols [lg*8, +8) (k2=0) and [32 + lg*8, +8) (k2=1): 4 x float4 = 64 B/lane.
#define LOADRAW(R_, T_)                                                         \
    {                                                                           \
        const float* p_ = cb + (size_t)((T_) * 16 + l15) * C_DIM + lg * 8;      \
        R_[0] = *(const float4*)(p_);                                           \
        R_[1] = *(const float4*)(p_ + 4);                                       \
        R_[2] = *(const float4*)(p_ + 32);                                      \
        R_[3] = *(const float4*)(p_ + 36);                                      \
    }

// Split raw tile into A-frags (A[s*2+k2], same layout as the old prep) and
// run 32 MFMAs in 2 independent chains + argmax update.
#define SPLIT_COMPUTE(T_, R_)                                                   \
    {                                                                           \
        bf16x8 A[6];                                                            \
        split8(R_[0], R_[1], &A[0], &A[2], &A[4]);                              \
        split8(R_[2], R_[3], &A[1], &A[3], &A[5]);                              \
        f32x4 acc0 = zero4, acc1 = zero4;                                       \
        PASS8(A, acc0, 0)                                                       \
        PASS8(A, acc1, 1)                                                       \
        const int cbase = (T_) * 16 + lg * 4;                                   \
        _Pragma("unroll")                                                       \
        for (int r = 0; r < 4; ++r) {                                           \
            if (acc0[r] > best0) { best0 = acc0[r]; bi0 = cbase + r; }          \
            if (acc1[r] > best1) { best1 = acc1[r]; bi1 = cbase + r; }          \
        }                                                                       \
    }

// ---------------------------------------------------------------------------
// Single main kernel (R11): R6's proven loop shape (block = 128 rows, 4
// waves; wave w owns rows [w*32,+32) and scans all 2048 codes; 2-deep
// register ping-pong; no barriers in the loop), with the codebook bf16
// split done IN-LOOP from raw cb (kills the prep dispatch and its ~56us
// attached cost; ws 784KB -> 8.2KB). Split VALU (~290 instr/tile) co-issues
// with the MFMA pipe (m114). Last-finishing block finalizes loss/ppl inline.
// ---------------------------------------------------------------------------
__global__ __launch_bounds__(256, 2) void vq_mfma(
    const float* __restrict__ z, const float* __restrict__ cb,
    float* __restrict__ out, int* __restrict__ counts,
    float* __restrict__ loss_accum, int* __restrict__ done)
{
    __shared__ int   sidx[ROWS_B];
    __shared__ float wsum[4];
    __shared__ int   slast;

    const int tid  = threadIdx.x;
    const int lane = tid & 63;
    const int wv   = tid >> 6;            // 0..3
    const int l15  = lane & 15, lg = lane >> 4;
    const int row0 = blockIdx.x * ROWS_B; // 128 rows, same b for whole block
    const int b    = row0 >> 12;
    const int hw0  = row0 & 4095;
    const float* zb = z + (size_t)b * C_DIM * HW + hw0;

    if (tid == 0) slast = 0;

    // ---- build z B-fragments straight from global (coalesced 64B runs) ----
    bf16x8 zf[3][2][2];
#pragma unroll
    for (int nt = 0; nt < 2; ++nt) {
        const int row_l = wv * 32 + nt * 16 + l15;
#pragma unroll
        for (int k2 = 0; k2 < 2; ++k2) {
#pragma unroll
            for (int i = 0; i < 8; ++i) {
                float v = zb[(size_t)(k2 * 32 + lg * 8 + i) * HW + row_l];
                unsigned short s1 = f2bf(v);
                float r1 = v - bf2f(s1);
                unsigned short s2 = f2bf(r1);
                float r2 = r1 - bf2f(s2);
                zf[0][nt][k2][i] = (short)s1;
                zf[1][nt][k2][i] = (short)s2;
                zf[2][nt][k2][i] = (short)f2bf(r2);
            }
        }
    }

    // ---- main loop: 128 tiles, raw-cb loads, 2-deep ping-pong, in-loop
    // split, no barriers ----
    float best0 = -3.4e38f, best1 = -3.4e38f;
    int   bi0 = 0, bi1 = 0;
    const f32x4 zero4 = {0.f, 0.f, 0.f, 0.f};

    float4 Rc[4], Rn[4];
    LOADRAW(Rc, 0)

#pragma unroll 1
    for (int t = 0; t < NTILE; t += 2) {
        LOADRAW(Rn, t + 1)               // in flight under tile t's compute
        SPLIT_COMPUTE(t, Rc)
        if (t + 2 < NTILE) LOADRAW(Rc, t + 2)
        SPLIT_COMPUTE(t + 1, Rn)
    }

    // ---- merge lane-groups (code sub-index) per chain via shfl ----
#pragma unroll
    for (int off = 16; off <= 32; off <<= 1) {
        float ob; int oi;
        ob = __shfl_xor(best0, off, 64); oi = __shfl_xor(bi0, off, 64);
        if (ob > best0 || (ob == best0 && oi < bi0)) { best0 = ob; bi0 = oi; }
        ob = __shfl_xor(best1, off, 64); oi = __shfl_xor(bi1, off, 64);
        if (ob > best1 || (ob == best1 && oi < bi1)) { best1 = ob; bi1 = oi; }
    }
    if (lane < 32) {
        // lanes {l15, l15+16, l15+32, l15+48} agree; chain = lane>>4
        const int nt = lane >> 4;
        const int row_l = wv * 32 + lane;          // = wv*32 + nt*16 + l15
        const int ii = (nt == 0) ? bi0 : bi1;
        sidx[row_l] = ii;
        out[OUT_IDX_OFF + row0 + row_l] = (float)ii;
        atomicAdd(&counts[ii], 1);
    }
    __syncthreads();

    // ---- fused epilogue: gather cb[idx], ST-write, loss partial ----
    float* ob0 = out + (size_t)b * C_DIM * HW + hw0;
    float lsum = 0.f;
#pragma unroll
    for (int j = 0; j < 8; ++j) {
        const int m = j * 256 + tid;               // [0,2048) float4 units
        const int r = m & 127, c4 = m >> 7;
        const float4 q4 = *(const float4*)(cb + (size_t)sidx[r] * C_DIM + c4 * 4);
#pragma unroll
        for (int q = 0; q < 4; ++q) {
            const int c = c4 * 4 + q;
            const float zv = zb[(size_t)c * HW + r];
            const float qv = (q == 0) ? q4.x : (q == 1) ? q4.y : (q == 2) ? q4.z : q4.w;
            const float d = qv - zv;               // same fp order as reference ST
            lsum += d * d;
            ob0[(size_t)c * HW + r] = zv + d;
        }
    }
    for (int off = 32; off > 0; off >>= 1) lsum += __shfl_down(lsum, off, 64);
    if (lane == 0) wsum[wv] = lsum;
    __syncthreads();

    // ---- last-block inline finalize (proven R8) ----
    if (tid == 0) {
        atomicAdd(loss_accum, wsum[0] + wsum[1] + wsum[2] + wsum[3]);
        __threadfence();                            // publish counts + loss
        const int tk = atomicAdd(done, 1);
        if (tk == NBLOCKS - 1) slast = 1;
    }
    __syncthreads();
    if (slast) {
        __threadfence();                            // acquire side
        float h = 0.f;
        for (int e = tid; e < N_E; e += 256) {
            const int cnt = atomicAdd(&counts[e], 0);   // device-scope read
            const float em = (float)cnt * (1.0f / (float)NROWS);
            h -= em * logf(em + 1e-10f);
        }
        for (int off = 32; off > 0; off >>= 1) h += __shfl_down(h, off, 64);
        if (lane == 0) wsum[wv] = h;
        __syncthreads();
        if (tid == 0) {
            const float H = wsum[0] + wsum[1] + wsum[2] + wsum[3];
            const float L = atomicAdd(loss_accum, 0.f); // device-scope read
            const float m = L * (1.0f / (float)N_ELEM);
            out[OUT_LOSS_OFF] = 0.25f * m + m;   // BETA*mean + mean
            out[OUT_PPL_OFF]  = expf(H);
        }
    }
}

extern "C" void kernel_launch(void* const* d_in, const int* in_sizes, int n_in,
                              void* d_out, int out_size, void* d_ws, size_t ws_size,
                              hipStream_t stream)
{
    const float* z  = (const float*)d_in[0];
    const float* cb = (const float*)d_in[1];
    float* out = (float*)d_out;

    // ws layout: counts[2048] int | loss f32 | done int  (8200 bytes total)
    int*   counts     = (int*)d_ws;
    float* loss_accum = (float*)((char*)d_ws + N_E * sizeof(int));
    int*   done       = (int*)((char*)d_ws + N_E * sizeof(int) + 4);

    hipMemsetAsync(d_ws, 0, N_E * sizeof(int) + 8, stream);
    vq_mfma<<<NBLOCKS, 256, 0, stream>>>(z, cb, out, counts, loss_accum, done);
}

// Round 12
// 207.398 us; speedup vs baseline: 1.1680x; 1.1680x over previous
//
#include <hip/hip_runtime.h>

// Problem constants (z: [16, 64, 64, 64] f32, codebook: [2048, 64] f32)
#define C_DIM   64
#define HW      4096        // H*W
#define NROWS   65536       // B*H*W
#define N_E     2048
#define N_ELEM  4194304     // B*C*H*W
// Output layout (flat): z_q_out 4194304 | loss 1 | perplexity 1 | indices 65536
#define OUT_LOSS_OFF 4194304
#define OUT_PPL_OFF  4194305
#define OUT_IDX_OFF  4194306

#define ROWS_B   128                 // rows per block -> 512 blocks = 2/CU
#define NBLOCKS  (NROWS / ROWS_B)    // 512
#define NTILE32  (N_E / 32)          // 64 code tiles of 32 codes
#define TILE_U   768                 // bf16x8 units per tile (12 frags x 64 lanes)

typedef __attribute__((ext_vector_type(8)))  short bf16x8;
typedef __attribute__((ext_vector_type(16))) float f32x16;

// round-to-nearest-even f32 -> bf16 bits
__device__ __forceinline__ unsigned short f2bf(float f) {
    unsigned u = __float_as_uint(f);
    return (unsigned short)((u + 0x7FFFu + ((u >> 16) & 1u)) >> 16);
}
__device__ __forceinline__ float bf2f(unsigned short b) {
    return __uint_as_float(((unsigned)b) << 16);
}

// ---------------------------------------------------------------------------
// Prep (coalesced, 32x32 fragment order). One thread per (tile, ks, lane):
// reads 32B contiguous of cb, writes 3 x 16B frag chunks (1KB contiguous per
// wave-store). A-frag layout for mfma_f32_32x32x16_bf16: lane holds
// code = lane&31, k = ks*16 + (lane>>5)*8 + i. Element offset:
// ((tile*3 + s)*4 + ks)*512 + lane*8 + i. Zeroes counts/loss/ticket.
// ---------------------------------------------------------------------------
__global__ __launch_bounds__(256) void vq_prep(
    const float* __restrict__ cb, unsigned short* __restrict__ cbp,
    int* __restrict__ counts, float* __restrict__ loss_accum,
    int* __restrict__ done)
{
    const int u = blockIdx.x * 256 + threadIdx.x;   // [0, 16384)
    if (u < N_E) counts[u] = 0;
    if (u == 0)  { *loss_accum = 0.f; *done = 0; }

    const int lane = u & 63;
    const int ks   = (u >> 6) & 3;
    const int tile = u >> 8;                        // [0,64)
    const int code = tile * 32 + (lane & 31);
    const int k0   = ks * 16 + (lane >> 5) * 8;

    const float4 va = *(const float4*)(cb + (size_t)code * C_DIM + k0);
    const float4 vb = *(const float4*)(cb + (size_t)code * C_DIM + k0 + 4);
    const float v[8] = {va.x, va.y, va.z, va.w, vb.x, vb.y, vb.z, vb.w};

    bf16x8 s1v, s2v, s3v;
#pragma unroll
    for (int i = 0; i < 8; ++i) {                   // static indices only
        const unsigned short s1 = f2bf(v[i]);
        const float r1 = v[i] - bf2f(s1);
        const unsigned short s2 = f2bf(r1);
        const float r2 = r1 - bf2f(s2);
        s1v[i] = (short)s1;
        s2v[i] = (short)s2;
        s3v[i] = (short)f2bf(r2);
    }
    // s stride = 4*512 elems; frag f = s*4+ks at ((tile*3+s)*4+ks)*512
    const size_t base = ((size_t)(tile * 3 + 0) * 4 + ks) * 512 + (size_t)lane * 8;
    *(bf16x8*)(cbp + base)        = s1v;
    *(bf16x8*)(cbp + base + 2048) = s2v;
    *(bf16x8*)(cbp + base + 4096) = s3v;
}

#define M32(A_, B_, C_) __builtin_amdgcn_mfma_f32_32x32x16_bf16((A_), (B_), (C_), 0, 0, 0)

// one split-pass (sc,sz): 4 MFMAs over the 4 k-steps, 2 acc chains for ILP
#define P32(AA, SC, SZ)                                                         \
    accA = M32(AA[(SC) * 4 + 0], zf[SZ][0], accA);                              \
    accA = M32(AA[(SC) * 4 + 1], zf[SZ][1], accA);                              \
    accB = M32(AA[(SC) * 4 + 2], zf[SZ][2], accB);                              \
    accB = M32(AA[(SC) * 4 + 3], zf[SZ][3], accB);

// per-tile: 8 split-passes (0,0)(0,1)(1,0)(1,1)(0,2)(2,0)(1,2)(2,1) = 32 MFMA,
// then argmax over the 32 codes. D layout (m74/m101): z-row = lane&31,
// code_in_tile = (reg&3) + 8*(reg>>2) + 4*(lane>>5) -> increasing in reg.
#define COMPUTE_TILE32(T_, AA)                                                  \
    {                                                                           \
        f32x16 accA = zero16, accB = zero16;                                    \
        P32(AA, 0, 0) P32(AA, 0, 1) P32(AA, 1, 0) P32(AA, 1, 1)                 \
        P32(AA, 0, 2) P32(AA, 2, 0) P32(AA, 1, 2) P32(AA, 2, 1)                 \
        _Pragma("unroll")                                                       \
        for (int reg = 0; reg < 16; ++reg) {                                    \
            const float v = accA[reg] + accB[reg];                              \
            const int code = (T_) * 32 + (reg & 3) + 8 * (reg >> 2) + 4 * lh;   \
            if (v > best) { best = v; bi = code; }                              \
        }                                                                       \
    }

// load the 12 A-frags of tile T_ (12 x global_load_dwordx4, coalesced)
#define LOADA(AA, T_)                                                           \
    {                                                                           \
        const bf16x8* p_ = cbpf + (size_t)(T_) * TILE_U;                        \
        _Pragma("unroll")                                                       \
        for (int f = 0; f < 12; ++f) AA[f] = p_[f * 64 + lane];                 \
    }

// ---------------------------------------------------------------------------
// Main kernel. Block = 128 rows, 4 waves; wave w owns rows [w*32,+32) and
// scans all 2048 codes in 64 tiles of 32. 32x32x16 MFMA halves instruction
// count vs 16x16x32 at a 15% higher ceiling. 2-deep A ping-pong with
// sched_barrier(0) pinning load issue (R6/R10 showed the compiler otherwise
// sinks prefetch loads to their uses: VGPR 64 proved the pipeline never
// existed). No barriers in the loop. Last block finalizes loss/ppl inline.
// ---------------------------------------------------------------------------
__global__ __launch_bounds__(256, 2) void vq_mfma(
    const float* __restrict__ z, const float* __restrict__ cb,
    const unsigned short* __restrict__ cbp, float* __restrict__ out,
    int* __restrict__ counts, float* __restrict__ loss_accum,
    int* __restrict__ done)
{
    __shared__ int   sidx[ROWS_B];
    __shared__ float wsum[4];
    __shared__ int   slast;

    const int tid  = threadIdx.x;
    const int lane = tid & 63;
    const int wv   = tid >> 6;            // 0..3
    const int l31  = lane & 31, lh = lane >> 5;
    const int row0 = blockIdx.x * ROWS_B; // 128 rows, same b for whole block
    const int b    = row0 >> 12;
    const int hw0  = row0 & 4095;
    const float* zb = z + (size_t)b * C_DIM * HW + hw0;

    if (tid == 0) slast = 0;

    // ---- build z B-fragments (B: n=z-row=lane&31, k=ks*16+lh*8+i) from
    // global: per (ks,lh,i) the 32 lanes read 32 consecutive rows = 128B ----
    bf16x8 zf[3][4];
    {
        const int row_l = wv * 32 + l31;
#pragma unroll
        for (int ks = 0; ks < 4; ++ks) {
#pragma unroll
            for (int i = 0; i < 8; ++i) {
                float v = zb[(size_t)(ks * 16 + lh * 8 + i) * HW + row_l];
                unsigned short s1 = f2bf(v);
                float r1 = v - bf2f(s1);
                unsigned short s2 = f2bf(r1);
                float r2 = r1 - bf2f(s2);
                zf[0][ks][i] = (short)s1;
                zf[1][ks][i] = (short)s2;
                zf[2][ks][i] = (short)f2bf(r2);
            }
        }
    }

    // ---- main loop: 64 tiles, pinned 2-deep register ping-pong ----
    const bf16x8* cbpf = (const bf16x8*)cbp;
    float best = -3.4e38f;
    int   bi   = 0;
    const f32x16 zero16 = {0,0,0,0,0,0,0,0,0,0,0,0,0,0,0,0};

    bf16x8 Acur[12], Anxt[12];
    LOADA(Acur, 0)

#pragma unroll 1
    for (int t = 0; t < NTILE32; t += 2) {
        LOADA(Anxt, t + 1)                        // t+1 <= 63 always
        __builtin_amdgcn_sched_barrier(0);        // pin: loads issue BEFORE compute
        COMPUTE_TILE32(t, Acur)
        if (t + 2 < NTILE32) LOADA(Acur, t + 2)
        __builtin_amdgcn_sched_barrier(0);
        COMPUTE_TILE32(t + 1, Anxt)
    }

    // ---- merge: lanes l and l^32 hold same z-row, disjoint codes ----
    {
        const float ob = __shfl_xor(best, 32, 64);
        const int   oi = __shfl_xor(bi, 32, 64);
        if (ob > best || (ob == best && oi < bi)) { best = ob; bi = oi; }
    }
    if (lane < 32) {
        const int row_l = wv * 32 + lane;
        sidx[row_l] = bi;
        out[OUT_IDX_OFF + row0 + row_l] = (float)bi;
        atomicAdd(&counts[bi], 1);
    }
    __syncthreads();

    // ---- fused epilogue: gather cb[idx], ST-write, loss partial ----
    float* ob0 = out + (size_t)b * C_DIM * HW + hw0;
    float lsum = 0.f;
#pragma unroll
    for (int j = 0; j < 8; ++j) {
        const int m = j * 256 + tid;               // [0,2048) float4 units
        const int r = m & 127, c4 = m >> 7;
        const float4 q4 = *(const float4*)(cb + (size_t)sidx[r] * C_DIM + c4 * 4);
#pragma unroll
        for (int q = 0; q < 4; ++q) {
            const int c = c4 * 4 + q;
            const float zv = zb[(size_t)c * HW + r];
            const float qv = (q == 0) ? q4.x : (q == 1) ? q4.y : (q == 2) ? q4.z : q4.w;
            const float d = qv - zv;               // same fp order as reference ST
            lsum += d * d;
            ob0[(size_t)c * HW + r] = zv + d;
        }
    }
    for (int off = 32; off > 0; off >>= 1) lsum += __shfl_down(lsum, off, 64);
    if (lane == 0) wsum[wv] = lsum;
    __syncthreads();

    // ---- last-block inline finalize (proven R8) ----
    if (tid == 0) {
        atomicAdd(loss_accum, wsum[0] + wsum[1] + wsum[2] + wsum[3]);
        __threadfence();                            // publish counts + loss
        const int tk = atomicAdd(done, 1);
        if (tk == NBLOCKS - 1) slast = 1;
    }
    __syncthreads();
    if (slast) {
        __threadfence();                            // acquire side
        float h = 0.f;
        for (int e = tid; e < N_E; e += 256) {
            const int cnt = atomicAdd(&counts[e], 0);   // device-scope read
            const float em = (float)cnt * (1.0f / (float)NROWS);
            h -= em * logf(em + 1e-10f);
        }
        for (int off = 32; off > 0; off >>= 1) h += __shfl_down(h, off, 64);
        if (lane == 0) wsum[wv] = h;
        __syncthreads();
        if (tid == 0) {
            const float H = wsum[0] + wsum[1] + wsum[2] + wsum[3];
            const float L = atomicAdd(loss_accum, 0.f); // device-scope read
            const float m = L * (1.0f / (float)N_ELEM);
            out[OUT_LOSS_OFF] = 0.25f * m + m;   // BETA*mean + mean
            out[OUT_PPL_OFF]  = expf(H);
        }
    }
}

extern "C" void kernel_launch(void* const* d_in, const int* in_sizes, int n_in,
                              void* d_out, int out_size, void* d_ws, size_t ws_size,
                              hipStream_t stream)
{
    const float* z  = (const float*)d_in[0];
    const float* cb = (const float*)d_in[1];
    float* out = (float*)d_out;

    // ws: counts[2048] int | loss f32 | done int | pad | cbp bf16 (768KB) @16KB
    int*            counts     = (int*)d_ws;
    float*          loss_accum = (float*)((char*)d_ws + N_E * sizeof(int));
    int*            done       = (int*)((char*)d_ws + N_E * sizeof(int) + 4);
    unsigned short* cbp        = (unsigned short*)((char*)d_ws + 16384);

    vq_prep<<<64, 256, 0, stream>>>(cb, cbp, counts, loss_accum, done);
    vq_mfma<<<NBLOCKS, 256, 0, stream>>>(z, cb, cbp, out, counts, loss_accum, done);
}